// Round 4
// baseline (238.565 us; speedup 1.0000x reference)
//
#include <hip/hip_runtime.h>
#include <hip/hip_bf16.h>

typedef __attribute__((ext_vector_type(8))) short short8;
typedef __attribute__((ext_vector_type(4))) float f32x4;
typedef __attribute__((ext_vector_type(4))) unsigned short ushort4v;
typedef unsigned short u16;

#define MFMA32(a, b, c) __builtin_amdgcn_mfma_f32_16x16x32_bf16((a), (b), (c), 0, 0, 0)

__device__ __forceinline__ u16 f2bf(float f) {
    union { float f; unsigned int u; } v; v.f = f;
    unsigned int r = v.u + 0x7FFFu + ((v.u >> 16) & 1u);   // RNE
    return (u16)(r >> 16);
}

// Per-t-tile attention: QK^T -> softmax -> dropout -> PV -> store.
// qf slots use the "projection-natural" h-order: slot(lg,i) -> h = 32ks + 16*(i>=4) + 4lg + (i&3).
// k is read from LDS with the same permuted slot mapping (two b64 per ks), so no q transpose is needed.
template<int MAXST>
__device__ __forceinline__ void do_tile(int Tb, int nst, int lr, int lg,
                                        const short8* qf,            // [2] ks-frags
                                        const u16 (*lk)[72],
                                        const u16 (*wv)[264],        // holds v^T here
                                        u16* pbw,                    // wave-private [16][36]
                                        const float* mb, float* ob)
{
    f32x4 S[MAXST];
    #pragma unroll
    for (int st = 0; st < MAXST; ++st) {
        if (st < nst) {
            const u16* kr = &lk[16 * st + lr][0];
            ushort4v t0 = *(const ushort4v*)&kr[4 * lg];
            ushort4v t1 = *(const ushort4v*)&kr[16 + 4 * lg];
            ushort4v t2 = *(const ushort4v*)&kr[32 + 4 * lg];
            ushort4v t3 = *(const ushort4v*)&kr[48 + 4 * lg];
            short8 kf0, kf1;
            kf0[0]=(short)t0[0]; kf0[1]=(short)t0[1]; kf0[2]=(short)t0[2]; kf0[3]=(short)t0[3];
            kf0[4]=(short)t1[0]; kf0[5]=(short)t1[1]; kf0[6]=(short)t1[2]; kf0[7]=(short)t1[3];
            kf1[0]=(short)t2[0]; kf1[1]=(short)t2[1]; kf1[2]=(short)t2[2]; kf1[3]=(short)t2[3];
            kf1[4]=(short)t3[0]; kf1[5]=(short)t3[1]; kf1[6]=(short)t3[2]; kf1[7]=(short)t3[3];
            f32x4 a = (f32x4){0.f, 0.f, 0.f, 0.f};
            a = MFMA32(qf[0], kf0, a);
            a = MFMA32(qf[1], kf1, a);
            S[st] = a;
        }
    }

    // softmax rows t = Tb+4lg+j; cols s = 16st+lr (st regs x lr lanes)
    float mx[4], sum[4], rs[4];
    #pragma unroll
    for (int j = 0; j < 4; ++j) { mx[j] = -1e30f; sum[j] = 0.f; }

    const int tb = Tb + 4 * lg;
    #pragma unroll
    for (int st = 0; st < MAXST; ++st) {
        if (st < nst) {
            const int s = 16 * st + lr;
            #pragma unroll
            for (int j = 0; j < 4; ++j) {
                float Lv = (s <= tb + j) ? S[st][j] * 0.125f : -1e30f;
                S[st][j] = Lv;
                mx[j] = fmaxf(mx[j], Lv);
            }
        }
    }
    #pragma unroll
    for (int d = 1; d < 16; d <<= 1)
        #pragma unroll
        for (int j = 0; j < 4; ++j)
            mx[j] = fmaxf(mx[j], __shfl_xor(mx[j], d, 64));

    #pragma unroll
    for (int st = 0; st < MAXST; ++st) {
        if (st < nst) {
            #pragma unroll
            for (int j = 0; j < 4; ++j) {
                float p = exp2f((S[st][j] - mx[j]) * 1.44269504f);
                S[st][j] = p;
                sum[j] += p;
            }
        }
    }

    // prefetch chunk-0 dropout masks (fly under the sum reduction)
    float pm[2][4];
    #pragma unroll
    for (int sl = 0; sl < 2; ++sl) {
        if (sl < nst) {
            #pragma unroll
            for (int j = 0; j < 4; ++j)
                pm[sl][j] = mb[(size_t)(tb + j) * 256 + 16 * sl + lr];
        }
    }

    #pragma unroll
    for (int d = 1; d < 16; d <<= 1)
        #pragma unroll
        for (int j = 0; j < 4; ++j)
            sum[j] += __shfl_xor(sum[j], d, 64);
    #pragma unroll
    for (int j = 0; j < 4; ++j)
        rs[j] = 1.33333333333f / sum[j];     // (1/sum) * 1/(1-0.25)

    // PV: out^T = v^T @ P^T in 32-wide s-chunks
    f32x4 O[4];
    #pragma unroll
    for (int ht = 0; ht < 4; ++ht) O[ht] = (f32x4){0.f, 0.f, 0.f, 0.f};

    constexpr int NCH = (MAXST + 1) / 2;
    #pragma unroll
    for (int c = 0; c < NCH; ++c) {
        if (2 * c < nst) {
            float nm[2][4] = {{0.f,0.f,0.f,0.f},{0.f,0.f,0.f,0.f}};
            #pragma unroll
            for (int sl = 0; sl < 2; ++sl) {
                const int st = 2 * (c + 1) + sl;
                if (st < nst) {
                    #pragma unroll
                    for (int j = 0; j < 4; ++j)
                        nm[sl][j] = mb[(size_t)(tb + j) * 256 + 16 * st + lr];
                }
            }
            // P -> bf16 -> wave-private P^T (t-major [16][36]); zero-pad odd tail
            #pragma unroll
            for (int sl = 0; sl < 2; ++sl) {
                const int st = 2 * c + sl;
                #pragma unroll
                for (int j = 0; j < 4; ++j) {
                    float p = 0.f;
                    if (st < nst)
                        p = (pm[sl][j] >= 0.25f) ? S[st][j] * rs[j] : 0.f;
                    pbw[(4 * lg + j) * 36 + 16 * sl + lr] = f2bf(p);
                }
            }
            asm volatile("s_waitcnt lgkmcnt(0)" ::: "memory");
            __builtin_amdgcn_sched_barrier(0);
            // B-frag of P^T (natural slots): P[t=lr][s=32c+8lg+i] -> two b64
            ushort4v p0 = *(const ushort4v*)&pbw[lr * 36 + 8 * lg];
            ushort4v p1 = *(const ushort4v*)&pbw[lr * 36 + 8 * lg + 4];
            short8 pf;
            pf[0]=(short)p0[0]; pf[1]=(short)p0[1]; pf[2]=(short)p0[2]; pf[3]=(short)p0[3];
            pf[4]=(short)p1[0]; pf[5]=(short)p1[1]; pf[6]=(short)p1[2]; pf[7]=(short)p1[3];
            #pragma unroll
            for (int ht = 0; ht < 4; ++ht) {
                short8 vf = *(const short8*)&wv[16 * ht + lr][32 * c + 8 * lg];
                O[ht] = MFMA32(vf, pf, O[ht]);
            }
            #pragma unroll
            for (int sl = 0; sl < 2; ++sl)
                #pragma unroll
                for (int j = 0; j < 4; ++j)
                    pm[sl][j] = nm[sl][j];
        }
    }

    // epilogue: out[t][h], contiguous float4 per lane
    #pragma unroll
    for (int ht = 0; ht < 4; ++ht)
        *(f32x4*)&ob[(Tb + lr) * 64 + 16 * ht + 4 * lg] = O[ht];
}

// stage W^T bf16 into wv: lane l owns row n=l; wave w owns chunks c0=8(w+8i)
#define STAGE_W(Wm) do {                                                     \
    _Pragma("unroll")                                                        \
    for (int i_ = 0; i_ < 4; ++i_) {                                         \
        const int c0_ = 8 * (w + 8 * i_);                                    \
        short8 t_;                                                           \
        _Pragma("unroll")                                                    \
        for (int j_ = 0; j_ < 8; ++j_)                                       \
            t_[j_] = (short)f2bf((Wm)[(size_t)(c0_ + j_) * 64 + l]);         \
        *(short8*)&wv[l][c0_] = t_;                                          \
    } } while (0)

// One workgroup per batch; 8 waves; wave w owns 16-row t-tiles {w, 15-w} (17 s-tiles each).
// LDS = 78 KB -> 2 blocks/CU -> 4 waves/SIMD.
__global__ __launch_bounds__(512, 4)
void attn_head_fused(const float* __restrict__ x,
                     const float* __restrict__ Wq,
                     const float* __restrict__ Wk,
                     const float* __restrict__ Wv,
                     const float* __restrict__ dmask,
                     float* __restrict__ out)
{
    __shared__ u16 lk[256][72];      // k [s][h]                36864 B
    __shared__ u16 wv[64][264];      // W^T (proj) / v^T (attn) 33792 B
    __shared__ u16 pb[8][16][36];    // per-wave P^T             9216 B

    const int b   = blockIdx.x;
    const int tid = threadIdx.x;
    const int w   = tid >> 6;
    const int l   = tid & 63;
    const int lr  = l & 15;
    const int lg  = l >> 4;

    const int TbA  = 16 * w;
    const int TbB  = 16 * (15 - w);
    const int nst0 = w + 1;          // <= 8
    const int nst1 = 16 - w;         // <= 16

    const float* xb = x + (size_t)b * (256 * 256);

    // ---- x A-fragments for both tiles (reused by all three projections) ----
    short8 af[2][8];
    #pragma unroll
    for (int ti = 0; ti < 2; ++ti) {
        const float* xr = xb + (size_t)((ti ? TbB : TbA) + lr) * 256 + lg * 8;
        #pragma unroll
        for (int ks = 0; ks < 8; ++ks) {
            f32x4 a0 = *(const f32x4*)(xr + ks * 32);
            f32x4 a1 = *(const f32x4*)(xr + ks * 32 + 4);
            short8 f;
            f[0] = (short)f2bf(a0[0]); f[1] = (short)f2bf(a0[1]);
            f[2] = (short)f2bf(a0[2]); f[3] = (short)f2bf(a0[3]);
            f[4] = (short)f2bf(a1[0]); f[5] = (short)f2bf(a1[1]);
            f[6] = (short)f2bf(a1[2]); f[7] = (short)f2bf(a1[3]);
            af[ti][ks] = f;
        }
    }

    // ---- k projection (normal operands), nj-outer ----
    STAGE_W(Wk);
    __syncthreads();
    #pragma unroll
    for (int nj = 0; nj < 4; ++nj) {
        f32x4 a0 = (f32x4){0.f,0.f,0.f,0.f}, a1 = a0;
        #pragma unroll
        for (int ks = 0; ks < 8; ++ks) {
            short8 bf = *(const short8*)&wv[16 * nj + lr][ks * 32 + lg * 8];
            a0 = MFMA32(af[0][ks], bf, a0);
            a1 = MFMA32(af[1][ks], bf, a1);
        }
        const int n = 16 * nj + lr;
        #pragma unroll
        for (int j = 0; j < 4; ++j) {
            lk[TbA + 4 * lg + j][n] = f2bf(a0[j]);
            lk[TbB + 4 * lg + j][n] = f2bf(a1[j]);
        }
    }
    __syncthreads();

    // ---- q projection (SWAPPED operands -> q^T frags, no LDS round-trip) ----
    STAGE_W(Wq);
    __syncthreads();
    short8 qf[2][2];
    #pragma unroll
    for (int nj = 0; nj < 4; ++nj) {
        f32x4 a0 = (f32x4){0.f,0.f,0.f,0.f}, a1 = a0;
        #pragma unroll
        for (int ks = 0; ks < 8; ++ks) {
            short8 bf = *(const short8*)&wv[16 * nj + lr][ks * 32 + lg * 8];
            a0 = MFMA32(bf, af[0][ks], a0);   // A = W^T-frag, B = x-frag
            a1 = MFMA32(bf, af[1][ks], a1);
        }
        // lane holds q[t=Tb+lr][h=16nj+4lg+j] -> qf[ti][nj>>1] slots (nj&1)*4+j
        #pragma unroll
        for (int j = 0; j < 4; ++j) {
            qf[0][nj >> 1][(nj & 1) * 4 + j] = (short)f2bf(a0[j]);
            qf[1][nj >> 1][(nj & 1) * 4 + j] = (short)f2bf(a1[j]);
        }
    }
    __syncthreads();

    // ---- v projection (normal operands); v^T overwrites the W^T buffer ----
    STAGE_W(Wv);
    __syncthreads();
    f32x4 va[2][4];
    #pragma unroll
    for (int nj = 0; nj < 4; ++nj) {
        f32x4 a0 = (f32x4){0.f,0.f,0.f,0.f}, a1 = a0;
        #pragma unroll
        for (int ks = 0; ks < 8; ++ks) {
            short8 bf = *(const short8*)&wv[16 * nj + lr][ks * 32 + lg * 8];
            a0 = MFMA32(af[0][ks], bf, a0);
            a1 = MFMA32(af[1][ks], bf, a1);
        }
        va[0][nj] = a0;
        va[1][nj] = a1;
    }
    __syncthreads();            // all W^T reads drained before overwrite
    #pragma unroll
    for (int ti = 0; ti < 2; ++ti) {
        const int s0 = (ti ? TbB : TbA) + 4 * lg;
        #pragma unroll
        for (int nj = 0; nj < 4; ++nj) {
            ushort4v pk;
            pk[0] = f2bf(va[ti][nj][0]);
            pk[1] = f2bf(va[ti][nj][1]);
            pk[2] = f2bf(va[ti][nj][2]);
            pk[3] = f2bf(va[ti][nj][3]);
            *(ushort4v*)&wv[16 * nj + lr][s0] = pk;
        }
    }
    __syncthreads();

    // ---- attention, two balanced t-tiles per wave ----
    const float* mb = dmask + (size_t)b * (256 * 256);
    float* ob = out + (size_t)b * (256 * 64);
    u16* pbw = &pb[w][0][0];

    do_tile<8>(TbA, nst0, lr, lg, qf[0], lk, wv, pbw, mb, ob);
    do_tile<16>(TbB, nst1, lr, lg, qf[1], lk, wv, pbw, mb, ob);
}

extern "C" void kernel_launch(void* const* d_in, const int* in_sizes, int n_in,
                              void* d_out, int out_size, void* d_ws, size_t ws_size,
                              hipStream_t stream) {
    const float* x  = (const float*)d_in[0];
    const float* Wq = (const float*)d_in[1];
    const float* Wk = (const float*)d_in[2];
    const float* Wv = (const float*)d_in[3];
    const float* dm = (const float*)d_in[4];
    float* outp     = (float*)d_out;
    attn_head_fused<<<dim3(512), dim3(512), 0, stream>>>(x, Wq, Wk, Wv, dm, outp);
}

// Round 5
// 93.754 us; speedup vs baseline: 2.5446x; 2.5446x over previous
//
#include <hip/hip_runtime.h>
#include <hip/hip_bf16.h>

typedef __attribute__((ext_vector_type(8))) short short8;
typedef __attribute__((ext_vector_type(4))) float f32x4;
typedef __attribute__((ext_vector_type(4))) unsigned short ushort4v;
typedef unsigned short u16;

#define MFMA32(a, b, c) __builtin_amdgcn_mfma_f32_16x16x32_bf16((a), (b), (c), 0, 0, 0)

__device__ __forceinline__ u16 f2bf(float f) {
    union { float f; unsigned int u; } v; v.f = f;
    unsigned int r = v.u + 0x7FFFu + ((v.u >> 16) & 1u);   // RNE
    return (u16)(r >> 16);
}

// Flash-style per-t-tile attention: s processed in chunks of 8 s-tiles (128 s),
// running max/sum, PV in 32-s subchunks through a wave-private P^T LDS buffer.
// qf slots are "projection-natural": slot(lg,i) -> h = 32ks + 16*(i>=4) + 4lg + (i&3);
// k is read with the matching permuted slot mapping (4 x b64 per s-tile).
template<int NCHUNK>
__device__ __forceinline__ void do_tile(int Tb, int nst, int lr, int lg,
                                        const short8* qf,           // [2]
                                        const u16 (*lk)[72],
                                        const u16 (*lvT)[264],
                                        u16* pbw,                   // wave-private [16][40]
                                        const float* mb, float* ob)
{
    const int tb = Tb + 4 * lg;
    float m[4], ls[4];
    f32x4 O[4];
    #pragma unroll
    for (int j = 0; j < 4; ++j) { m[j] = -1e30f; ls[j] = 0.f; }
    #pragma unroll
    for (int ht = 0; ht < 4; ++ht) O[ht] = (f32x4){0.f, 0.f, 0.f, 0.f};

    #pragma unroll
    for (int c = 0; c < NCHUNK; ++c) {
        // ---- QK^T for this chunk (8 s-tiles) ----
        f32x4 S[8];
        #pragma unroll
        for (int sl = 0; sl < 8; ++sl) {
            const int st = 8 * c + sl;
            if (st < nst) {
                const u16* kr = &lk[16 * st + lr][0];
                ushort4v t0 = *(const ushort4v*)&kr[4 * lg];
                ushort4v t1 = *(const ushort4v*)&kr[16 + 4 * lg];
                ushort4v t2 = *(const ushort4v*)&kr[32 + 4 * lg];
                ushort4v t3 = *(const ushort4v*)&kr[48 + 4 * lg];
                short8 kf0, kf1;
                kf0[0]=(short)t0[0]; kf0[1]=(short)t0[1]; kf0[2]=(short)t0[2]; kf0[3]=(short)t0[3];
                kf0[4]=(short)t1[0]; kf0[5]=(short)t1[1]; kf0[6]=(short)t1[2]; kf0[7]=(short)t1[3];
                kf1[0]=(short)t2[0]; kf1[1]=(short)t2[1]; kf1[2]=(short)t2[2]; kf1[3]=(short)t2[3];
                kf1[4]=(short)t3[0]; kf1[5]=(short)t3[1]; kf1[6]=(short)t3[2]; kf1[7]=(short)t3[3];
                f32x4 a = (f32x4){0.f, 0.f, 0.f, 0.f};
                a = MFMA32(qf[0], kf0, a);
                a = MFMA32(qf[1], kf1, a);
                S[sl] = a;
            } else {
                S[sl] = (f32x4){-1e30f, -1e30f, -1e30f, -1e30f};
            }
        }

        // ---- scale + causal mask + chunk max ----
        float cm[4];
        #pragma unroll
        for (int j = 0; j < 4; ++j) cm[j] = m[j];
        #pragma unroll
        for (int sl = 0; sl < 8; ++sl) {
            const int st = 8 * c + sl;
            if (st < nst) {
                const int s = 16 * st + lr;
                #pragma unroll
                for (int j = 0; j < 4; ++j) {
                    float Lv = (s <= tb + j) ? S[sl][j] * 0.125f : -1e30f;
                    S[sl][j] = Lv;
                    cm[j] = fmaxf(cm[j], Lv);
                }
            }
        }
        #pragma unroll
        for (int d = 1; d < 16; d <<= 1)
            #pragma unroll
            for (int j = 0; j < 4; ++j)
                cm[j] = fmaxf(cm[j], __shfl_xor(cm[j], d, 64));

        // ---- rescale running state (tile-B chunk 1 only) ----
        float fs[4];
        if (c > 0) {
            #pragma unroll
            for (int j = 0; j < 4; ++j)
                fs[j] = exp2f((m[j] - cm[j]) * 1.44269504f);
            // O's t-dim lives on lanes (t = Tb+lr): redistribute per-row factor
            float fsel = (lr & 3) == 0 ? fs[0] : (lr & 3) == 1 ? fs[1]
                       : (lr & 3) == 2 ? fs[2] : fs[3];
            float fO = __shfl(fsel, ((lr >> 2) << 4) | lr, 64);
            #pragma unroll
            for (int ht = 0; ht < 4; ++ht) O[ht] *= fO;
        }
        #pragma unroll
        for (int j = 0; j < 4; ++j) m[j] = cm[j];

        // ---- exp + chunk sum ----
        float cs[4] = {0.f, 0.f, 0.f, 0.f};
        #pragma unroll
        for (int sl = 0; sl < 8; ++sl) {
            const int st = 8 * c + sl;
            if (st < nst) {
                #pragma unroll
                for (int j = 0; j < 4; ++j) {
                    float p = exp2f((S[sl][j] - m[j]) * 1.44269504f);
                    S[sl][j] = p;
                    cs[j] += p;
                }
            }
        }

        // prefetch subchunk-0 dropout masks (fly under the sum reduction)
        float pm[2][4];
        #pragma unroll
        for (int sl = 0; sl < 2; ++sl) {
            const int st = 8 * c + sl;
            if (st < nst) {
                #pragma unroll
                for (int j = 0; j < 4; ++j)
                    pm[sl][j] = mb[(size_t)(tb + j) * 256 + 16 * st + lr];
            }
        }

        #pragma unroll
        for (int d = 1; d < 16; d <<= 1)
            #pragma unroll
            for (int j = 0; j < 4; ++j)
                cs[j] += __shfl_xor(cs[j], d, 64);
        #pragma unroll
        for (int j = 0; j < 4; ++j)
            ls[j] = (c > 0 ? ls[j] * fs[j] : 0.f) + cs[j];

        // ---- PV: 4 subchunks of 32 s ----
        #pragma unroll
        for (int sc = 0; sc < 4; ++sc) {
            const int st0 = 8 * c + 2 * sc;
            if (st0 < nst) {
                float nm[2][4] = {{0.f,0.f,0.f,0.f},{0.f,0.f,0.f,0.f}};
                #pragma unroll
                for (int sl = 0; sl < 2; ++sl) {
                    const int stn = st0 + 2 + sl;
                    if (sc < 3 && stn < nst) {
                        #pragma unroll
                        for (int j = 0; j < 4; ++j)
                            nm[sl][j] = mb[(size_t)(tb + j) * 256 + 16 * stn + lr];
                    }
                }
                // unnormalized P (masked) -> bf16 -> wave-private P^T (t-major)
                #pragma unroll
                for (int sl = 0; sl < 2; ++sl) {
                    const int st = st0 + sl;
                    #pragma unroll
                    for (int j = 0; j < 4; ++j) {
                        float p = 0.f;
                        if (st < nst)
                            p = (pm[sl][j] >= 0.25f) ? S[2 * sc + sl][j] : 0.f;
                        pbw[(4 * lg + j) * 40 + 16 * sl + lr] = f2bf(p);
                    }
                }
                asm volatile("s_waitcnt lgkmcnt(0)" ::: "memory");
                __builtin_amdgcn_sched_barrier(0);
                short8 pf = *(const short8*)&pbw[lr * 40 + 8 * lg];
                #pragma unroll
                for (int ht = 0; ht < 4; ++ht) {
                    short8 vf = *(const short8*)&lvT[16 * ht + lr][128 * c + 32 * sc + 8 * lg];
                    O[ht] = MFMA32(vf, pf, O[ht]);
                }
                #pragma unroll
                for (int sl = 0; sl < 2; ++sl)
                    #pragma unroll
                    for (int j = 0; j < 4; ++j)
                        pm[sl][j] = nm[sl][j];
            }
        }
    }

    // ---- final normalize (per t = lane) + store ----
    float rs[4];
    #pragma unroll
    for (int j = 0; j < 4; ++j)
        rs[j] = 1.33333333333f / ls[j];     // (1/sum) * 1/(1-0.25)
    float rsel = (lr & 3) == 0 ? rs[0] : (lr & 3) == 1 ? rs[1]
               : (lr & 3) == 2 ? rs[2] : rs[3];
    float rfin = __shfl(rsel, ((lr >> 2) << 4) | lr, 64);
    #pragma unroll
    for (int ht = 0; ht < 4; ++ht) {
        f32x4 o = O[ht] * rfin;
        *(f32x4*)&ob[(size_t)(Tb + lr) * 64 + 16 * ht + 4 * lg] = o;
    }
}

// One workgroup per batch; 8 waves; wave w owns t-tiles {w, 15-w} (17 s-tiles total).
// LDS = 80896 B -> 2 blocks/CU -> 4 waves/SIMD; structured to fit 128 VGPRs.
__global__ __launch_bounds__(512, 4)
void attn_head_fused(const float* __restrict__ x,
                     const float* __restrict__ Wq,
                     const float* __restrict__ Wk,
                     const float* __restrict__ Wv,
                     const float* __restrict__ dmask,
                     float* __restrict__ out)
{
    __shared__ u16 lk[256][72];       // k [s][h]        36864 B
    __shared__ u16 lvT[64][264];      // v^T [h][s]      33792 B
    __shared__ union {
        u16 pwt[64][72];              // W^T piece (projection)   9216 B
        u16 pb[8][16][40];            // per-wave P^T (attention) 10240 B
    } sp;

    const int b   = blockIdx.x;
    const int tid = threadIdx.x;
    const int w   = tid >> 6;
    const int l   = tid & 63;
    const int lr  = l & 15;
    const int lg  = l >> 4;

    const int TbA  = 16 * w;
    const int TbB  = 16 * (15 - w);
    const int nst0 = w + 1;           // <= 8  -> 1 chunk
    const int nst1 = 16 - w;          // <= 16 -> 2 chunks

    const float* xb = x + (size_t)b * (256 * 256);

    // ---- x A-fragments for both tiles (reused by all three projections) ----
    short8 af[2][8];
    #pragma unroll
    for (int ti = 0; ti < 2; ++ti) {
        const float* xr = xb + (size_t)((ti ? TbB : TbA) + lr) * 256 + lg * 8;
        #pragma unroll
        for (int ks = 0; ks < 8; ++ks) {
            f32x4 a0 = *(const f32x4*)(xr + ks * 32);
            f32x4 a1 = *(const f32x4*)(xr + ks * 32 + 4);
            short8 f;
            f[0] = (short)f2bf(a0[0]); f[1] = (short)f2bf(a0[1]);
            f[2] = (short)f2bf(a0[2]); f[3] = (short)f2bf(a0[3]);
            f[4] = (short)f2bf(a1[0]); f[5] = (short)f2bf(a1[1]);
            f[6] = (short)f2bf(a1[2]); f[7] = (short)f2bf(a1[3]);
            af[ti][ks] = f;
        }
    }

    f32x4 acc[2][4];

    // ================= k projection (normal operands) =================
    #pragma unroll
    for (int ti = 0; ti < 2; ++ti)
        #pragma unroll
        for (int nj = 0; nj < 4; ++nj) acc[ti][nj] = (f32x4){0.f,0.f,0.f,0.f};
    #pragma unroll
    for (int p = 0; p < 4; ++p) {
        __syncthreads();
        {   // stage piece p of Wk^T: lane l owns row n=l, wave w owns cols 8w..8w+7
            const int c0 = 64 * p + 8 * w;
            short8 t;
            #pragma unroll
            for (int j = 0; j < 8; ++j)
                t[j] = (short)f2bf(Wk[(size_t)(c0 + j) * 64 + l]);
            *(short8*)&sp.pwt[l][8 * w] = t;
        }
        __syncthreads();
        #pragma unroll
        for (int ks2 = 0; ks2 < 2; ++ks2)
            #pragma unroll
            for (int nj = 0; nj < 4; ++nj) {
                short8 bf = *(const short8*)&sp.pwt[16 * nj + lr][32 * ks2 + 8 * lg];
                acc[0][nj] = MFMA32(af[0][2 * p + ks2], bf, acc[0][nj]);
                acc[1][nj] = MFMA32(af[1][2 * p + ks2], bf, acc[1][nj]);
            }
    }
    #pragma unroll
    for (int nj = 0; nj < 4; ++nj) {
        const int n = 16 * nj + lr;
        #pragma unroll
        for (int j = 0; j < 4; ++j) {
            lk[TbA + 4 * lg + j][n] = f2bf(acc[0][nj][j]);
            lk[TbB + 4 * lg + j][n] = f2bf(acc[1][nj][j]);
        }
    }

    // ================= v projection (normal operands) =================
    #pragma unroll
    for (int ti = 0; ti < 2; ++ti)
        #pragma unroll
        for (int nj = 0; nj < 4; ++nj) acc[ti][nj] = (f32x4){0.f,0.f,0.f,0.f};
    #pragma unroll
    for (int p = 0; p < 4; ++p) {
        __syncthreads();
        {
            const int c0 = 64 * p + 8 * w;
            short8 t;
            #pragma unroll
            for (int j = 0; j < 8; ++j)
                t[j] = (short)f2bf(Wv[(size_t)(c0 + j) * 64 + l]);
            *(short8*)&sp.pwt[l][8 * w] = t;
        }
        __syncthreads();
        #pragma unroll
        for (int ks2 = 0; ks2 < 2; ++ks2)
            #pragma unroll
            for (int nj = 0; nj < 4; ++nj) {
                short8 bf = *(const short8*)&sp.pwt[16 * nj + lr][32 * ks2 + 8 * lg];
                acc[0][nj] = MFMA32(af[0][2 * p + ks2], bf, acc[0][nj]);
                acc[1][nj] = MFMA32(af[1][2 * p + ks2], bf, acc[1][nj]);
            }
    }
    #pragma unroll
    for (int ti = 0; ti < 2; ++ti) {
        const int s0 = (ti ? TbB : TbA) + 4 * lg;
        #pragma unroll
        for (int nj = 0; nj < 4; ++nj) {
            ushort4v pk;
            pk[0] = f2bf(acc[ti][nj][0]);
            pk[1] = f2bf(acc[ti][nj][1]);
            pk[2] = f2bf(acc[ti][nj][2]);
            pk[3] = f2bf(acc[ti][nj][3]);
            *(ushort4v*)&lvT[16 * nj + lr][s0] = pk;
        }
    }

    // ================= q projection (SWAPPED operands -> q^T frags) =================
    #pragma unroll
    for (int ti = 0; ti < 2; ++ti)
        #pragma unroll
        for (int nj = 0; nj < 4; ++nj) acc[ti][nj] = (f32x4){0.f,0.f,0.f,0.f};
    #pragma unroll
    for (int p = 0; p < 4; ++p) {
        __syncthreads();
        {
            const int c0 = 64 * p + 8 * w;
            short8 t;
            #pragma unroll
            for (int j = 0; j < 8; ++j)
                t[j] = (short)f2bf(Wq[(size_t)(c0 + j) * 64 + l]);
            *(short8*)&sp.pwt[l][8 * w] = t;
        }
        __syncthreads();
        #pragma unroll
        for (int ks2 = 0; ks2 < 2; ++ks2)
            #pragma unroll
            for (int nj = 0; nj < 4; ++nj) {
                short8 bf = *(const short8*)&sp.pwt[16 * nj + lr][32 * ks2 + 8 * lg];
                acc[0][nj] = MFMA32(bf, af[0][2 * p + ks2], acc[0][nj]);  // A=W^T, B=x
                acc[1][nj] = MFMA32(bf, af[1][2 * p + ks2], acc[1][nj]);
            }
    }
    short8 qf[2][2];
    #pragma unroll
    for (int nj = 0; nj < 4; ++nj) {
        #pragma unroll
        for (int j = 0; j < 4; ++j) {
            qf[0][nj >> 1][(nj & 1) * 4 + j] = (short)f2bf(acc[0][nj][j]);
            qf[1][nj >> 1][(nj & 1) * 4 + j] = (short)f2bf(acc[1][nj][j]);
        }
    }

    __syncthreads();   // lk, lvT visible; pwt dead -> pb may be written

    // ================= attention =================
    const float* mb = dmask + (size_t)b * (256 * 256);
    float* ob = out + (size_t)b * (256 * 64);
    u16* pbw = &sp.pb[w][0][0];

    do_tile<1>(TbA, nst0, lr, lg, qf[0], lk, lvT, pbw, mb, ob);
    do_tile<2>(TbB, nst1, lr, lg, qf[1], lk, lvT, pbw, mb, ob);
}

extern "C" void kernel_launch(void* const* d_in, const int* in_sizes, int n_in,
                              void* d_out, int out_size, void* d_ws, size_t ws_size,
                              hipStream_t stream) {
    const float* x  = (const float*)d_in[0];
    const float* Wq = (const float*)d_in[1];
    const float* Wk = (const float*)d_in[2];
    const float* Wv = (const float*)d_in[3];
    const float* dm = (const float*)d_in[4];
    float* outp     = (float*)d_out;
    attn_head_fused<<<dim3(512), dim3(512), 0, stream>>>(x, Wq, Wk, Wv, dm, outp);
}

// Round 6
// 74.885 us; speedup vs baseline: 3.1858x; 1.2520x over previous
//
#include <hip/hip_runtime.h>
#include <hip/hip_bf16.h>

typedef __attribute__((ext_vector_type(8))) short short8;
typedef __attribute__((ext_vector_type(4))) float f32x4;
typedef __attribute__((ext_vector_type(4))) unsigned short ushort4v;
typedef unsigned short u16;

#define MFMA32(a, b, c) __builtin_amdgcn_mfma_f32_16x16x32_bf16((a), (b), (c), 0, 0, 0)

__device__ __forceinline__ u16 f2bf(float f) {
    union { float f; unsigned int u; } v; v.f = f;
    unsigned int r = v.u + 0x7FFFu + ((v.u >> 16) & 1u);   // RNE
    return (u16)(r >> 16);
}

// Flash-style per-t-tile attention (verified in R5): s in chunks of 8 s-tiles,
// running max/sum, PV in 32-s subchunks via wave-private P^T LDS buffer.
// qf slots are "projection-natural": slot(lg,i) -> h = 32ks + 16*(i>=4) + 4lg + (i&3);
// k is read with the matching permuted slot mapping (4 x b64 per s-tile).
template<int NCHUNK>
__device__ __forceinline__ void do_tile(int Tb, int nst, int lr, int lg,
                                        const short8* qf,           // [2]
                                        const u16 (*lk)[72],
                                        const u16 (*lvT)[264],
                                        u16* pbw,                   // wave-private [16][40]
                                        const float* mb, float* ob)
{
    const int tb = Tb + 4 * lg;
    float m[4], ls[4];
    f32x4 O[4];
    #pragma unroll
    for (int j = 0; j < 4; ++j) { m[j] = -1e30f; ls[j] = 0.f; }
    #pragma unroll
    for (int ht = 0; ht < 4; ++ht) O[ht] = (f32x4){0.f, 0.f, 0.f, 0.f};

    #pragma unroll
    for (int c = 0; c < NCHUNK; ++c) {
        // ---- QK^T for this chunk ----
        f32x4 S[8];
        #pragma unroll
        for (int sl = 0; sl < 8; ++sl) {
            const int st = 8 * c + sl;
            if (st < nst) {
                const u16* kr = &lk[16 * st + lr][0];
                ushort4v t0 = *(const ushort4v*)&kr[4 * lg];
                ushort4v t1 = *(const ushort4v*)&kr[16 + 4 * lg];
                ushort4v t2 = *(const ushort4v*)&kr[32 + 4 * lg];
                ushort4v t3 = *(const ushort4v*)&kr[48 + 4 * lg];
                short8 kf0, kf1;
                kf0[0]=(short)t0[0]; kf0[1]=(short)t0[1]; kf0[2]=(short)t0[2]; kf0[3]=(short)t0[3];
                kf0[4]=(short)t1[0]; kf0[5]=(short)t1[1]; kf0[6]=(short)t1[2]; kf0[7]=(short)t1[3];
                kf1[0]=(short)t2[0]; kf1[1]=(short)t2[1]; kf1[2]=(short)t2[2]; kf1[3]=(short)t2[3];
                kf1[4]=(short)t3[0]; kf1[5]=(short)t3[1]; kf1[6]=(short)t3[2]; kf1[7]=(short)t3[3];
                f32x4 a = (f32x4){0.f, 0.f, 0.f, 0.f};
                a = MFMA32(qf[0], kf0, a);
                a = MFMA32(qf[1], kf1, a);
                S[sl] = a;
            } else {
                S[sl] = (f32x4){-1e30f, -1e30f, -1e30f, -1e30f};
            }
        }

        // ---- scale + causal mask + chunk max ----
        float cm[4];
        #pragma unroll
        for (int j = 0; j < 4; ++j) cm[j] = m[j];
        #pragma unroll
        for (int sl = 0; sl < 8; ++sl) {
            const int st = 8 * c + sl;
            if (st < nst) {
                const int s = 16 * st + lr;
                #pragma unroll
                for (int j = 0; j < 4; ++j) {
                    float Lv = (s <= tb + j) ? S[sl][j] * 0.125f : -1e30f;
                    S[sl][j] = Lv;
                    cm[j] = fmaxf(cm[j], Lv);
                }
            }
        }
        #pragma unroll
        for (int d = 1; d < 16; d <<= 1)
            #pragma unroll
            for (int j = 0; j < 4; ++j)
                cm[j] = fmaxf(cm[j], __shfl_xor(cm[j], d, 64));

        // ---- rescale running state (chunk 1+ only) ----
        float fs[4];
        if (c > 0) {
            #pragma unroll
            for (int j = 0; j < 4; ++j)
                fs[j] = exp2f((m[j] - cm[j]) * 1.44269504f);
            float fsel = (lr & 3) == 0 ? fs[0] : (lr & 3) == 1 ? fs[1]
                       : (lr & 3) == 2 ? fs[2] : fs[3];
            float fO = __shfl(fsel, ((lr >> 2) << 4) | lr, 64);
            #pragma unroll
            for (int ht = 0; ht < 4; ++ht) O[ht] *= fO;
        }
        #pragma unroll
        for (int j = 0; j < 4; ++j) m[j] = cm[j];

        // ---- exp + chunk sum ----
        float cs[4] = {0.f, 0.f, 0.f, 0.f};
        #pragma unroll
        for (int sl = 0; sl < 8; ++sl) {
            const int st = 8 * c + sl;
            if (st < nst) {
                #pragma unroll
                for (int j = 0; j < 4; ++j) {
                    float p = exp2f((S[sl][j] - m[j]) * 1.44269504f);
                    S[sl][j] = p;
                    cs[j] += p;
                }
            }
        }

        // prefetch subchunk-0 dropout masks (fly under the sum reduction)
        float pm[2][4];
        #pragma unroll
        for (int sl = 0; sl < 2; ++sl) {
            const int st = 8 * c + sl;
            if (st < nst) {
                #pragma unroll
                for (int j = 0; j < 4; ++j)
                    pm[sl][j] = mb[(size_t)(tb + j) * 256 + 16 * st + lr];
            }
        }

        #pragma unroll
        for (int d = 1; d < 16; d <<= 1)
            #pragma unroll
            for (int j = 0; j < 4; ++j)
                cs[j] += __shfl_xor(cs[j], d, 64);
        #pragma unroll
        for (int j = 0; j < 4; ++j)
            ls[j] = (c > 0 ? ls[j] * fs[j] : 0.f) + cs[j];

        // ---- PV: 4 subchunks of 32 s ----
        #pragma unroll
        for (int sc = 0; sc < 4; ++sc) {
            const int st0 = 8 * c + 2 * sc;
            if (st0 < nst) {
                float nm[2][4] = {{0.f,0.f,0.f,0.f},{0.f,0.f,0.f,0.f}};
                #pragma unroll
                for (int sl = 0; sl < 2; ++sl) {
                    const int stn = st0 + 2 + sl;
                    if (sc < 3 && stn < nst) {
                        #pragma unroll
                        for (int j = 0; j < 4; ++j)
                            nm[sl][j] = mb[(size_t)(tb + j) * 256 + 16 * stn + lr];
                    }
                }
                #pragma unroll
                for (int sl = 0; sl < 2; ++sl) {
                    const int st = st0 + sl;
                    #pragma unroll
                    for (int j = 0; j < 4; ++j) {
                        float p = 0.f;
                        if (st < nst)
                            p = (pm[sl][j] >= 0.25f) ? S[2 * sc + sl][j] : 0.f;
                        pbw[(4 * lg + j) * 40 + 16 * sl + lr] = f2bf(p);
                    }
                }
                asm volatile("s_waitcnt lgkmcnt(0)" ::: "memory");
                __builtin_amdgcn_sched_barrier(0);
                short8 pf = *(const short8*)&pbw[lr * 40 + 8 * lg];
                #pragma unroll
                for (int ht = 0; ht < 4; ++ht) {
                    short8 vf = *(const short8*)&lvT[16 * ht + lr][128 * c + 32 * sc + 8 * lg];
                    O[ht] = MFMA32(vf, pf, O[ht]);
                }
                #pragma unroll
                for (int sl = 0; sl < 2; ++sl)
                    #pragma unroll
                    for (int j = 0; j < 4; ++j)
                        pm[sl][j] = nm[sl][j];
            }
        }
    }

    // ---- final normalize + store ----
    float rs[4];
    #pragma unroll
    for (int j = 0; j < 4; ++j)
        rs[j] = 1.33333333333f / ls[j];     // (1/sum) * 1/(1-0.25)
    float rsel = (lr & 3) == 0 ? rs[0] : (lr & 3) == 1 ? rs[1]
               : (lr & 3) == 2 ? rs[2] : rs[3];
    float rfin = __shfl(rsel, ((lr >> 2) << 4) | lr, 64);
    #pragma unroll
    for (int ht = 0; ht < 4; ++ht) {
        f32x4 o = O[ht] * rfin;
        *(f32x4*)&ob[(size_t)(Tb + lr) * 64 + 16 * ht + 4 * lg] = o;
    }
}

// One workgroup per batch; 8 waves; wave w owns t-tiles {w, 15-w}.
// TWO-PASS projection: pass 0 projects tile w, pass 1 tile 15-w -> only one
// af[8] (32 regs) + one acc[4] (16) live at a time; fits 128 unified regs.
// LDS = 80896 B -> 2 blocks/CU.
__global__ __launch_bounds__(512, 4)
void attn_head_fused(const float* __restrict__ x,
                     const float* __restrict__ Wq,
                     const float* __restrict__ Wk,
                     const float* __restrict__ Wv,
                     const float* __restrict__ dmask,
                     float* __restrict__ out)
{
    __shared__ __align__(16) u16 lk[256][72];       // k [s][h]        36864 B
    __shared__ __align__(16) u16 lvT[64][264];      // v^T [h][s]      33792 B
    __shared__ __align__(16) union {
        u16 pwt[64][72];              // W^T piece (projection)   9216 B
        u16 pb[8][16][40];            // per-wave P^T (attention) 10240 B
    } sp;

    const int b   = blockIdx.x;
    const int tid = threadIdx.x;
    const int w   = tid >> 6;
    const int l   = tid & 63;
    const int lr  = l & 15;
    const int lg  = l >> 4;

    const float* xb = x + (size_t)b * (256 * 256);
    short8 qf[2][2];

    #pragma unroll
    for (int P = 0; P < 2; ++P) {
        const int Tb = P ? 16 * (15 - w) : 16 * w;

        // ---- x A-fragments for this pass's tile ----
        short8 af[8];
        {
            const float* xr = xb + (size_t)(Tb + lr) * 256 + lg * 8;
            #pragma unroll
            for (int ks = 0; ks < 8; ++ks) {
                f32x4 a0 = *(const f32x4*)(xr + ks * 32);
                f32x4 a1 = *(const f32x4*)(xr + ks * 32 + 4);
                short8 f;
                f[0] = (short)f2bf(a0[0]); f[1] = (short)f2bf(a0[1]);
                f[2] = (short)f2bf(a0[2]); f[3] = (short)f2bf(a0[3]);
                f[4] = (short)f2bf(a1[0]); f[5] = (short)f2bf(a1[1]);
                f[6] = (short)f2bf(a1[2]); f[7] = (short)f2bf(a1[3]);
                af[ks] = f;
            }
        }

        // ---- k projection ----
        {
            f32x4 acc[4];
            #pragma unroll
            for (int nj = 0; nj < 4; ++nj) acc[nj] = (f32x4){0.f,0.f,0.f,0.f};
            #pragma unroll
            for (int p = 0; p < 4; ++p) {
                __syncthreads();
                const int c0 = 64 * p + 8 * w;
                short8 t;
                #pragma unroll
                for (int j = 0; j < 8; ++j)
                    t[j] = (short)f2bf(Wk[(size_t)(c0 + j) * 64 + l]);
                *(short8*)&sp.pwt[l][8 * w] = t;
                __syncthreads();
                #pragma unroll
                for (int ks2 = 0; ks2 < 2; ++ks2)
                    #pragma unroll
                    for (int nj = 0; nj < 4; ++nj) {
                        short8 bf = *(const short8*)&sp.pwt[16 * nj + lr][32 * ks2 + 8 * lg];
                        acc[nj] = MFMA32(af[2 * p + ks2], bf, acc[nj]);
                    }
            }
            #pragma unroll
            for (int nj = 0; nj < 4; ++nj) {
                const int n = 16 * nj + lr;
                #pragma unroll
                for (int j = 0; j < 4; ++j)
                    lk[Tb + 4 * lg + j][n] = f2bf(acc[nj][j]);
            }
        }

        // ---- v projection ----
        {
            f32x4 acc[4];
            #pragma unroll
            for (int nj = 0; nj < 4; ++nj) acc[nj] = (f32x4){0.f,0.f,0.f,0.f};
            #pragma unroll
            for (int p = 0; p < 4; ++p) {
                __syncthreads();
                const int c0 = 64 * p + 8 * w;
                short8 t;
                #pragma unroll
                for (int j = 0; j < 8; ++j)
                    t[j] = (short)f2bf(Wv[(size_t)(c0 + j) * 64 + l]);
                *(short8*)&sp.pwt[l][8 * w] = t;
                __syncthreads();
                #pragma unroll
                for (int ks2 = 0; ks2 < 2; ++ks2)
                    #pragma unroll
                    for (int nj = 0; nj < 4; ++nj) {
                        short8 bf = *(const short8*)&sp.pwt[16 * nj + lr][32 * ks2 + 8 * lg];
                        acc[nj] = MFMA32(af[2 * p + ks2], bf, acc[nj]);
                    }
            }
            const int s0 = Tb + 4 * lg;
            #pragma unroll
            for (int nj = 0; nj < 4; ++nj) {
                ushort4v pk;
                pk[0] = f2bf(acc[nj][0]);
                pk[1] = f2bf(acc[nj][1]);
                pk[2] = f2bf(acc[nj][2]);
                pk[3] = f2bf(acc[nj][3]);
                *(ushort4v*)&lvT[16 * nj + lr][s0] = pk;
            }
        }

        // ---- q projection (SWAPPED operands -> q^T frags, no LDS round-trip) ----
        {
            f32x4 acc[4];
            #pragma unroll
            for (int nj = 0; nj < 4; ++nj) acc[nj] = (f32x4){0.f,0.f,0.f,0.f};
            #pragma unroll
            for (int p = 0; p < 4; ++p) {
                __syncthreads();
                const int c0 = 64 * p + 8 * w;
                short8 t;
                #pragma unroll
                for (int j = 0; j < 8; ++j)
                    t[j] = (short)f2bf(Wq[(size_t)(c0 + j) * 64 + l]);
                *(short8*)&sp.pwt[l][8 * w] = t;
                __syncthreads();
                #pragma unroll
                for (int ks2 = 0; ks2 < 2; ++ks2)
                    #pragma unroll
                    for (int nj = 0; nj < 4; ++nj) {
                        short8 bf = *(const short8*)&sp.pwt[16 * nj + lr][32 * ks2 + 8 * lg];
                        acc[nj] = MFMA32(bf, af[2 * p + ks2], acc[nj]);  // A=W^T, B=x
                    }
            }
            #pragma unroll
            for (int nj = 0; nj < 4; ++nj)
                #pragma unroll
                for (int j = 0; j < 4; ++j)
                    qf[P][nj >> 1][(nj & 1) * 4 + j] = (short)f2bf(acc[nj][j]);
        }
    }

    __syncthreads();   // lk, lvT complete; pwt dead -> pb may be written

    // ================= attention =================
    const int nst0 = w + 1;           // tile A = w       -> 1 chunk
    const int nst1 = 16 - w;          // tile B = 15 - w  -> 2 chunks
    const float* mb = dmask + (size_t)b * (256 * 256);
    float* ob = out + (size_t)b * (256 * 64);
    u16* pbw = &sp.pb[w][0][0];

    do_tile<1>(16 * w,        nst0, lr, lg, qf[0], lk, lvT, pbw, mb, ob);
    do_tile<2>(16 * (15 - w), nst1, lr, lg, qf[1], lk, lvT, pbw, mb, ob);
}

extern "C" void kernel_launch(void* const* d_in, const int* in_sizes, int n_in,
                              void* d_out, int out_size, void* d_ws, size_t ws_size,
                              hipStream_t stream) {
    const float* x  = (const float*)d_in[0];
    const float* Wq = (const float*)d_in[1];
    const float* Wk = (const float*)d_in[2];
    const float* Wv = (const float*)d_in[3];
    const float* dm = (const float*)d_in[4];
    float* outp     = (float*)d_out;
    attn_head_fused<<<dim3(512), dim3(512), 0, stream>>>(x, Wq, Wk, Wv, dm, outp);
}

// Round 7
// 68.028 us; speedup vs baseline: 3.5069x; 1.1008x over previous
//
#include <hip/hip_runtime.h>
#include <hip/hip_bf16.h>

typedef __attribute__((ext_vector_type(8))) short short8;
typedef __attribute__((ext_vector_type(4))) float f32x4;
typedef __attribute__((ext_vector_type(4))) unsigned short ushort4v;
typedef unsigned short u16;

#define MFMA32(a, b, c) __builtin_amdgcn_mfma_f32_16x16x32_bf16((a), (b), (c), 0, 0, 0)

__device__ __forceinline__ u16 f2bf(float f) {
    union { float f; unsigned int u; } v; v.f = f;
    unsigned int r = v.u + 0x7FFFu + ((v.u >> 16) & 1u);   // RNE
    return (u16)(r >> 16);
}

// Rolled flash attention for one 16-row t-tile. Runtime chunk count -> small,
// I$-resident loop body shared by all waves. qf slots are "projection-natural":
// slot(lg,i) -> h = 32ks + 16*(i>=4) + 4lg + (i&3); k read with matching
// permuted slot mapping (4 x b64 per s-tile). All mappings verified R3-R6.
__device__ __forceinline__ void do_tile(int Tb, int nst, int lr, int lg,
                                        const short8* qf,           // [2]
                                        const u16 (*lk)[72],
                                        const u16 (*lvT)[264],
                                        u16* pbw,                   // wave-private [16][40]
                                        const float* mb, float* ob)
{
    const int tb = Tb + 4 * lg;
    float m[4], ls[4];
    f32x4 O[4];
    #pragma unroll
    for (int j = 0; j < 4; ++j) { m[j] = -1e30f; ls[j] = 0.f; }
    #pragma unroll
    for (int ht = 0; ht < 4; ++ht) O[ht] = (f32x4){0.f, 0.f, 0.f, 0.f};

    // dropout masks for chunk 0 (prefetched; consumed late in first iteration)
    float pm[2][4];
    #pragma unroll
    for (int sl = 0; sl < 2; ++sl) {
        #pragma unroll
        for (int j = 0; j < 4; ++j) pm[sl][j] = 0.f;
        if (sl < nst) {
            #pragma unroll
            for (int j = 0; j < 4; ++j)
                pm[sl][j] = mb[(size_t)(tb + j) * 256 + 16 * sl + lr];
        }
    }

    #pragma unroll 1
    for (int c = 0; 2 * c < nst; ++c) {
        // prefetch next chunk's dropout masks (fly under this chunk's compute)
        float nm[2][4];
        #pragma unroll
        for (int sl = 0; sl < 2; ++sl) {
            const int stn = 2 * c + 2 + sl;
            #pragma unroll
            for (int j = 0; j < 4; ++j) nm[sl][j] = 0.f;
            if (stn < nst) {
                #pragma unroll
                for (int j = 0; j < 4; ++j)
                    nm[sl][j] = mb[(size_t)(tb + j) * 256 + 16 * stn + lr];
            }
        }

        // ---- QK^T for s-tiles 2c, 2c+1 ----
        // odd-tail subtile (st == nst) is always causally dead (16*nst > Tb+15),
        // so the causal mask below zeroes it with no extra branch. Row index
        // stays < 256 for all reachable (w, tile) combos.
        f32x4 S[2];
        #pragma unroll
        for (int sl = 0; sl < 2; ++sl) {
            const u16* kr = &lk[16 * (2 * c + sl) + lr][0];
            ushort4v t0 = *(const ushort4v*)&kr[4 * lg];
            ushort4v t1 = *(const ushort4v*)&kr[16 + 4 * lg];
            ushort4v t2 = *(const ushort4v*)&kr[32 + 4 * lg];
            ushort4v t3 = *(const ushort4v*)&kr[48 + 4 * lg];
            short8 kf0, kf1;
            kf0[0]=(short)t0[0]; kf0[1]=(short)t0[1]; kf0[2]=(short)t0[2]; kf0[3]=(short)t0[3];
            kf0[4]=(short)t1[0]; kf0[5]=(short)t1[1]; kf0[6]=(short)t1[2]; kf0[7]=(short)t1[3];
            kf1[0]=(short)t2[0]; kf1[1]=(short)t2[1]; kf1[2]=(short)t2[2]; kf1[3]=(short)t2[3];
            kf1[4]=(short)t3[0]; kf1[5]=(short)t3[1]; kf1[6]=(short)t3[2]; kf1[7]=(short)t3[3];
            f32x4 a = (f32x4){0.f, 0.f, 0.f, 0.f};
            a = MFMA32(qf[0], kf0, a);
            a = MFMA32(qf[1], kf1, a);
            S[sl] = a;
        }

        // ---- scale + causal mask + chunk max ----
        float cm[4];
        #pragma unroll
        for (int j = 0; j < 4; ++j) cm[j] = m[j];
        #pragma unroll
        for (int sl = 0; sl < 2; ++sl) {
            const int s = 16 * (2 * c + sl) + lr;
            #pragma unroll
            for (int j = 0; j < 4; ++j) {
                float Lv = (s <= tb + j) ? S[sl][j] * 0.125f : -1e30f;
                S[sl][j] = Lv;
                cm[j] = fmaxf(cm[j], Lv);
            }
        }
        #pragma unroll
        for (int d = 1; d < 16; d <<= 1)
            #pragma unroll
            for (int j = 0; j < 4; ++j)
                cm[j] = fmaxf(cm[j], __shfl_xor(cm[j], d, 64));

        // ---- rescale running state (fs == 0 on first chunk since m = -1e30) ----
        float fs[4];
        #pragma unroll
        for (int j = 0; j < 4; ++j)
            fs[j] = exp2f((m[j] - cm[j]) * 1.44269504f);
        {
            float fsel = (lr & 3) == 0 ? fs[0] : (lr & 3) == 1 ? fs[1]
                       : (lr & 3) == 2 ? fs[2] : fs[3];
            float fO = __shfl(fsel, ((lr >> 2) << 4) | lr, 64);
            #pragma unroll
            for (int ht = 0; ht < 4; ++ht) O[ht] *= fO;
        }
        #pragma unroll
        for (int j = 0; j < 4; ++j) m[j] = cm[j];

        // ---- exp + chunk sum ----
        float cs[4] = {0.f, 0.f, 0.f, 0.f};
        #pragma unroll
        for (int sl = 0; sl < 2; ++sl)
            #pragma unroll
            for (int j = 0; j < 4; ++j) {
                float p = exp2f((S[sl][j] - m[j]) * 1.44269504f);
                S[sl][j] = p;
                cs[j] += p;
            }
        #pragma unroll
        for (int d = 1; d < 16; d <<= 1)
            #pragma unroll
            for (int j = 0; j < 4; ++j)
                cs[j] += __shfl_xor(cs[j], d, 64);
        #pragma unroll
        for (int j = 0; j < 4; ++j)
            ls[j] = ls[j] * fs[j] + cs[j];

        // ---- dropout + pack -> wave-private P^T (t-major [16][40]) ----
        #pragma unroll
        for (int sl = 0; sl < 2; ++sl)
            #pragma unroll
            for (int j = 0; j < 4; ++j) {
                float p = (pm[sl][j] >= 0.25f) ? S[sl][j] : 0.f;
                pbw[(4 * lg + j) * 40 + 16 * sl + lr] = f2bf(p);
            }
        asm volatile("s_waitcnt lgkmcnt(0)" ::: "memory");
        __builtin_amdgcn_sched_barrier(0);
        short8 pf = *(const short8*)&pbw[lr * 40 + 8 * lg];
        #pragma unroll
        for (int ht = 0; ht < 4; ++ht) {
            short8 vf = *(const short8*)&lvT[16 * ht + lr][32 * c + 8 * lg];
            O[ht] = MFMA32(vf, pf, O[ht]);
        }
        #pragma unroll
        for (int sl = 0; sl < 2; ++sl)
            #pragma unroll
            for (int j = 0; j < 4; ++j)
                pm[sl][j] = nm[sl][j];
    }

    // ---- final normalize + store ----
    float rs[4];
    #pragma unroll
    for (int j = 0; j < 4; ++j)
        rs[j] = 1.33333333333f / ls[j];     // (1/sum) * 1/(1-0.25)
    float rsel = (lr & 3) == 0 ? rs[0] : (lr & 3) == 1 ? rs[1]
               : (lr & 3) == 2 ? rs[2] : rs[3];
    float rfin = __shfl(rsel, ((lr >> 2) << 4) | lr, 64);
    #pragma unroll
    for (int ht = 0; ht < 4; ++ht) {
        f32x4 o = O[ht] * rfin;
        *(f32x4*)&ob[(size_t)(Tb + lr) * 64 + 16 * ht + 4 * lg] = o;
    }
}

// stage full W^T bf16 into wt: lane l owns row n=l; wave w owns chunks 8(w+8i)
#define STAGE_W(Wm) do {                                                     \
    _Pragma("unroll")                                                        \
    for (int i_ = 0; i_ < 4; ++i_) {                                         \
        const int c0_ = 8 * (w + 8 * i_);                                    \
        short8 t_;                                                           \
        _Pragma("unroll")                                                    \
        for (int j_ = 0; j_ < 8; ++j_)                                       \
            t_[j_] = (short)f2bf((Wm)[(size_t)(c0_ + j_) * 64 + l]);         \
        *(short8*)&wt[l][c0_] = t_;                                          \
    } } while (0)

// One workgroup per batch; 8 waves; wave w owns t-tiles {w, 15-w} (balanced).
// Full W^T staging once per matrix -> 5 barriers total; attention barrier-free.
// LDS = 114688 B -> 1 block/CU; launch_bounds(512,2) -> 256-reg budget, no spills.
__global__ __launch_bounds__(512, 2)
void attn_head_fused(const float* __restrict__ x,
                     const float* __restrict__ Wq,
                     const float* __restrict__ Wk,
                     const float* __restrict__ Wv,
                     const float* __restrict__ dmask,
                     float* __restrict__ out)
{
    __shared__ __align__(16) u16 lk[256][72];       // k [s][h]    36864 B
    __shared__ __align__(16) u16 lvT[64][264];      // v^T [h][s]  33792 B
    __shared__ __align__(16) u16 wt[64][264];       // W^T [n][c]  33792 B
    __shared__ __align__(16) u16 pb[8][16][40];     // per-wave P^T 10240 B

    const int b   = blockIdx.x;
    const int tid = threadIdx.x;
    const int w   = tid >> 6;
    const int l   = tid & 63;
    const int lr  = l & 15;
    const int lg  = l >> 4;

    const int TbA = 16 * w;
    const int TbB = 16 * (15 - w);

    const float* xb = x + (size_t)b * (256 * 256);

    // ---- x A-fragments for both tiles (reused by all three projections) ----
    short8 af[2][8];
    #pragma unroll
    for (int ti = 0; ti < 2; ++ti) {
        const float* xr = xb + (size_t)((ti ? TbB : TbA) + lr) * 256 + lg * 8;
        #pragma unroll
        for (int ks = 0; ks < 8; ++ks) {
            f32x4 a0 = *(const f32x4*)(xr + ks * 32);
            f32x4 a1 = *(const f32x4*)(xr + ks * 32 + 4);
            short8 f;
            f[0] = (short)f2bf(a0[0]); f[1] = (short)f2bf(a0[1]);
            f[2] = (short)f2bf(a0[2]); f[3] = (short)f2bf(a0[3]);
            f[4] = (short)f2bf(a1[0]); f[5] = (short)f2bf(a1[1]);
            f[6] = (short)f2bf(a1[2]); f[7] = (short)f2bf(a1[3]);
            af[ti][ks] = f;
        }
    }

    f32x4 acc[2][4];

    // ================= k projection =================
    STAGE_W(Wk);
    __syncthreads();                                   // B1
    #pragma unroll
    for (int ti = 0; ti < 2; ++ti)
        #pragma unroll
        for (int nj = 0; nj < 4; ++nj) acc[ti][nj] = (f32x4){0.f,0.f,0.f,0.f};
    #pragma unroll
    for (int ks = 0; ks < 8; ++ks)
        #pragma unroll
        for (int nj = 0; nj < 4; ++nj) {
            short8 bf = *(const short8*)&wt[16 * nj + lr][ks * 32 + lg * 8];
            acc[0][nj] = MFMA32(af[0][ks], bf, acc[0][nj]);
            acc[1][nj] = MFMA32(af[1][ks], bf, acc[1][nj]);
        }
    #pragma unroll
    for (int nj = 0; nj < 4; ++nj) {
        const int n = 16 * nj + lr;
        #pragma unroll
        for (int j = 0; j < 4; ++j) {
            lk[TbA + 4 * lg + j][n] = f2bf(acc[0][nj][j]);
            lk[TbB + 4 * lg + j][n] = f2bf(acc[1][nj][j]);
        }
    }
    __syncthreads();                                   // B2 (wt readers done)

    // ================= v projection =================
    STAGE_W(Wv);
    __syncthreads();                                   // B3
    #pragma unroll
    for (int ti = 0; ti < 2; ++ti)
        #pragma unroll
        for (int nj = 0; nj < 4; ++nj) acc[ti][nj] = (f32x4){0.f,0.f,0.f,0.f};
    #pragma unroll
    for (int ks = 0; ks < 8; ++ks)
        #pragma unroll
        for (int nj = 0; nj < 4; ++nj) {
            short8 bf = *(const short8*)&wt[16 * nj + lr][ks * 32 + lg * 8];
            acc[0][nj] = MFMA32(af[0][ks], bf, acc[0][nj]);
            acc[1][nj] = MFMA32(af[1][ks], bf, acc[1][nj]);
        }
    #pragma unroll
    for (int ti = 0; ti < 2; ++ti) {
        const int s0 = (ti ? TbB : TbA) + 4 * lg;
        #pragma unroll
        for (int nj = 0; nj < 4; ++nj) {
            ushort4v pk;
            pk[0] = f2bf(acc[ti][nj][0]);
            pk[1] = f2bf(acc[ti][nj][1]);
            pk[2] = f2bf(acc[ti][nj][2]);
            pk[3] = f2bf(acc[ti][nj][3]);
            *(ushort4v*)&lvT[16 * nj + lr][s0] = pk;
        }
    }
    __syncthreads();                                   // B4 (wt readers done)

    // ================= q projection (SWAPPED operands -> q^T frags) =================
    STAGE_W(Wq);
    __syncthreads();                                   // B5 (also: lk/lvT visible)
    #pragma unroll
    for (int ti = 0; ti < 2; ++ti)
        #pragma unroll
        for (int nj = 0; nj < 4; ++nj) acc[ti][nj] = (f32x4){0.f,0.f,0.f,0.f};
    #pragma unroll
    for (int ks = 0; ks < 8; ++ks)
        #pragma unroll
        for (int nj = 0; nj < 4; ++nj) {
            short8 bf = *(const short8*)&wt[16 * nj + lr][ks * 32 + lg * 8];
            acc[0][nj] = MFMA32(bf, af[0][ks], acc[0][nj]);   // A=W^T, B=x
            acc[1][nj] = MFMA32(bf, af[1][ks], acc[1][nj]);
        }
    short8 qf[2][2];
    #pragma unroll
    for (int nj = 0; nj < 4; ++nj)
        #pragma unroll
        for (int j = 0; j < 4; ++j) {
            qf[0][nj >> 1][(nj & 1) * 4 + j] = (short)f2bf(acc[0][nj][j]);
            qf[1][nj >> 1][(nj & 1) * 4 + j] = (short)f2bf(acc[1][nj][j]);
        }

    // ================= attention (barrier-free, waves desync) =================
    const float* mb = dmask + (size_t)b * (256 * 256);
    float* ob = out + (size_t)b * (256 * 64);
    u16* pbw = &pb[w][0][0];

    do_tile(TbA, w + 1,  lr, lg, qf[0], lk, lvT, pbw, mb, ob);
    do_tile(TbB, 16 - w, lr, lg, qf[1], lk, lvT, pbw, mb, ob);
}

extern "C" void kernel_launch(void* const* d_in, const int* in_sizes, int n_in,
                              void* d_out, int out_size, void* d_ws, size_t ws_size,
                              hipStream_t stream) {
    const float* x  = (const float*)d_in[0];
    const float* Wq = (const float*)d_in[1];
    const float* Wk = (const float*)d_in[2];
    const float* Wv = (const float*)d_in[3];
    const float* dm = (const float*)d_in[4];
    float* outp     = (float*)d_out;
    attn_head_fused<<<dim3(512), dim3(512), 0, stream>>>(x, Wq, Wk, Wv, dm, outp);
}